// Round 1
// baseline (593.952 us; speedup 1.0000x reference)
//
#include <hip/hip_runtime.h>
#include <hip/hip_bf16.h>
#include <math.h>

// ---------------------------------------------------------------------------
// CrossAttnMLP fused implementation for gfx950.
// Pipeline: K0 (weight fp32->bf16 + zero stats) -> K1 (fused transformer body
// -> h1_pre + BN1 partial stats) -> K2 (BN1 apply + gelu + h2 GEMM + BN2
// stats) -> K3 (BN2 apply + gelu + final dot).
// ---------------------------------------------------------------------------

typedef __attribute__((ext_vector_type(8))) __bf16 bf16x8;
typedef __attribute__((ext_vector_type(8))) short s16x8;
typedef __attribute__((ext_vector_type(4))) float f32x4;

union S8U { s16x8 s; bf16x8 b; };

__device__ __forceinline__ short f2b(float f) {
  union { float f; unsigned u; } v; v.f = f;
  unsigned r = v.u + 0x7fffu + ((v.u >> 16) & 1u);   // RNE
  return (short)(r >> 16);
}
__device__ __forceinline__ float b2f(short s) {
  union { unsigned u; float f; } v; v.u = ((unsigned)(unsigned short)s) << 16;
  return v.f;
}
__device__ __forceinline__ float gelu_f(float x) {
  return 0.5f * x * (1.0f + erff(x * 0.7071067811865475f));
}

// One K=32 MFMA step over a 64-row x (NTS*16)-col tile for one wave.
// A: LDS bf16 (bits in short), row stride lda.  W: global bf16, row-major
// (out,k), row stride ldw.  Fragment layouts per cdna4 measured mappings.
template<int NTS>
__device__ __forceinline__ void mfma_step(const short* __restrict__ Abuf, int lda, int kkA,
                                          const short* __restrict__ W, int ldw, int kw,
                                          int colbase, int l16, int q,
                                          f32x4 (&acc)[4][NTS]) {
  S8U a[4];
#pragma unroll
  for (int mt = 0; mt < 4; ++mt)
    a[mt].s = *(const s16x8*)(Abuf + (16 * mt + l16) * lda + kkA + 8 * q);
#pragma unroll
  for (int nt = 0; nt < NTS; ++nt) {
    S8U b;
    b.s = *(const s16x8*)(W + (size_t)(colbase + 16 * nt + l16) * ldw + kw + 8 * q);
#pragma unroll
    for (int mt = 0; mt < 4; ++mt)
      acc[mt][nt] = __builtin_amdgcn_mfma_f32_16x16x32_bf16(a[mt].b, b.b, acc[mt][nt], 0, 0, 0);
  }
}

template<int NTS>
__device__ __forceinline__ void zero_acc(f32x4 (&acc)[4][NTS]) {
  f32x4 z = {0.f, 0.f, 0.f, 0.f};
#pragma unroll
  for (int mt = 0; mt < 4; ++mt)
#pragma unroll
    for (int nt = 0; nt < NTS; ++nt) acc[mt][nt] = z;
}

// Plain epilogue: + bias[col], optional gelu, store bf16 to LDS (stride 136).
__device__ __forceinline__ void epi_bias_store(f32x4 (&acc)[4][2], const float* __restrict__ bias,
                                               short* dst, int w, int l16, int q, bool do_gelu) {
#pragma unroll
  for (int nt = 0; nt < 2; ++nt) {
    int col = 32 * w + 16 * nt + l16;
    float bb = bias[col];
#pragma unroll
    for (int mt = 0; mt < 4; ++mt)
#pragma unroll
      for (int r = 0; r < 4; ++r) {
        int row = 16 * mt + 4 * q + r;
        float v = acc[mt][nt][r] + bb;
        if (do_gelu) v = gelu_f(v);
        dst[row * 136 + col] = f2b(v);
      }
  }
}

// Epilogue: acc += bias + residual(resbuf), LayerNorm over 128 cols, write dst.
// Row sums: 16-lane shuffle reduce (wave holds 32 of 128 cols) + LDS combine.
__device__ __forceinline__ void epi_res_ln(f32x4 (&acc)[4][2], const float* __restrict__ bias,
                                           const short* resbuf,
                                           const float* __restrict__ g, const float* __restrict__ bta,
                                           short* dst, float (*lnp)[4][2], float (*murs)[2],
                                           int w, int l16, int q, int tid) {
#pragma unroll
  for (int nt = 0; nt < 2; ++nt) {
    int col = 32 * w + 16 * nt + l16;
    float bb = bias[col];
#pragma unroll
    for (int mt = 0; mt < 4; ++mt)
#pragma unroll
      for (int r = 0; r < 4; ++r) {
        int row = 16 * mt + 4 * q + r;
        acc[mt][nt][r] += bb + b2f(resbuf[row * 136 + col]);
      }
  }
#pragma unroll
  for (int mt = 0; mt < 4; ++mt) {
#pragma unroll
    for (int r = 0; r < 4; ++r) {
      float v0 = acc[mt][0][r], v1 = acc[mt][1][r];
      float s = v0 + v1;
      float sq = v0 * v0 + v1 * v1;
#pragma unroll
      for (int off = 1; off < 16; off <<= 1) {
        s += __shfl_xor(s, off);
        sq += __shfl_xor(sq, off);
      }
      if (l16 == 0) {
        int row = 16 * mt + 4 * q + r;
        lnp[row][w][0] = s;
        lnp[row][w][1] = sq;
      }
    }
  }
  __syncthreads();
  if (tid < 64) {
    float s = lnp[tid][0][0] + lnp[tid][1][0] + lnp[tid][2][0] + lnp[tid][3][0];
    float sq = lnp[tid][0][1] + lnp[tid][1][1] + lnp[tid][2][1] + lnp[tid][3][1];
    float mu = s * (1.0f / 128.0f);
    float var = sq * (1.0f / 128.0f) - mu * mu;
    murs[tid][0] = mu;
    murs[tid][1] = rsqrtf(var + 1e-5f);
  }
  __syncthreads();
#pragma unroll
  for (int nt = 0; nt < 2; ++nt) {
    int col = 32 * w + 16 * nt + l16;
    float gg = g[col], b2 = bta[col];
#pragma unroll
    for (int mt = 0; mt < 4; ++mt)
#pragma unroll
      for (int r = 0; r < 4; ++r) {
        int row = 16 * mt + 4 * q + r;
        float v = (acc[mt][nt][r] - murs[row][0]) * murs[row][1] * gg + b2;
        dst[row * 136 + col] = f2b(v);
      }
  }
}

// FFN block: act = LN(act + W2 @ gelu(W1 @ act + b1) + b2), chunked over FF=512
// in 128-col slices through H so only one 64x128 h-buffer is live.
__device__ __forceinline__ void ffn_block(const short* __restrict__ w1, const short* __restrict__ w2,
                                          const float* __restrict__ b1, const float* __restrict__ b2,
                                          const float* __restrict__ g, const float* __restrict__ bta,
                                          short* act, short* H,
                                          float (*lnp)[4][2], float (*murs)[2],
                                          int w, int l16, int q, int tid) {
  f32x4 acc2[4][2];
  zero_acc(acc2);
  for (int c = 0; c < 4; ++c) {
    f32x4 acch[4][2];
    zero_acc(acch);
#pragma unroll
    for (int kk = 0; kk < 4; ++kk)
      mfma_step<2>(act, 136, 32 * kk, w1, 128, 32 * kk, c * 128 + 32 * w, l16, q, acch);
#pragma unroll
    for (int nt = 0; nt < 2; ++nt) {
      int lcol = 32 * w + 16 * nt + l16;
      float bb = b1[c * 128 + lcol];
#pragma unroll
      for (int mt = 0; mt < 4; ++mt)
#pragma unroll
        for (int r = 0; r < 4; ++r)
          H[(16 * mt + 4 * q + r) * 136 + lcol] = f2b(gelu_f(acch[mt][nt][r] + bb));
    }
    __syncthreads();
#pragma unroll
    for (int kk = 0; kk < 4; ++kk)
      mfma_step<2>(H, 136, 32 * kk, w2, 512, c * 128 + 32 * kk, 32 * w, l16, q, acc2);
    __syncthreads();
  }
  epi_res_ln(acc2, b2, act, g, bta, act, lnp, murs, w, l16, q, tid);
}

// ---------------------------------------------------------------------------
struct K1Args {
  const float* x;
  const short *wpep, *wtcr, *wvp, *wop, *wvt, *wot, *w1p, *w2p, *w1t, *w2t, *wh1;
  const float *bpep, *btcr, *bvp, *bop, *bvt, *bot;
  const float *g1p, *e1p, *g2p, *e2p, *g1t, *e1t, *g2t, *e2t;
  const float *b1p, *b2p, *b1t, *b2t, *bh1;
  float *sum1, *sq1;
  short* h1;
};

__global__ __launch_bounds__(256, 2) void k1_main(K1Args A) {
  // LDS: U,V,T,H 64x136 bf16 each (pad 128->136 => fragment reads hit all 32
  // banks); S = double-buffered x staging (64x40), overlaid with LN scratch.
  __shared__ __align__(16) short smem[4 * 64 * 136 + 2 * 64 * 40];
  short* U = smem;
  short* V = U + 64 * 136;
  short* T = V + 64 * 136;
  short* H = T + 64 * 136;
  short* S = H + 64 * 136;
  float (*lnp)[4][2] = (float (*)[4][2])(void*)S;          // 2048 B
  float (*murs)[2] = (float (*)[2])(void*)(S + 1024);      // 512 B

  const int tid = threadIdx.x;
  const int w = tid >> 6;
  const int lane = tid & 63;
  const int l16 = lane & 15;
  const int q = lane >> 4;
  const size_t row0 = (size_t)blockIdx.x * 64;

  auto stage = [&](int kbase, short* Sb) {
    int r = tid >> 2, c8 = (tid & 3) * 8;
    const float* p = A.x + (row0 + r) * 864 + kbase + c8;
    float4 f0 = *(const float4*)p;
    float4 f1 = *(const float4*)(p + 4);
    s16x8 o;
    o[0] = f2b(f0.x); o[1] = f2b(f0.y); o[2] = f2b(f0.z); o[3] = f2b(f0.w);
    o[4] = f2b(f1.x); o[5] = f2b(f1.y); o[6] = f2b(f1.z); o[7] = f2b(f1.w);
    *(s16x8*)(Sb + r * 40 + c8) = o;
  };

  f32x4 acc[4][2];

  // P1: pep = x[:, :384] @ w_pep^T + b_pep  -> U
  zero_acc(acc);
  for (int t = 0; t < 12; ++t) {
    stage(32 * t, S + (t & 1) * (64 * 40));
    __syncthreads();
    mfma_step<2>(S + (t & 1) * (64 * 40), 40, 0, A.wpep, 384, 32 * t, 32 * w, l16, q, acc);
  }
  epi_bias_store(acc, A.bpep, U, w, l16, q, false);

  // P2: tcr = x[:, 384:] @ w_tcr^T + b_tcr  -> V
  zero_acc(acc);
  for (int t = 0; t < 15; ++t) {
    stage(384 + 32 * t, S + (t & 1) * (64 * 40));
    __syncthreads();
    mfma_step<2>(S + (t & 1) * (64 * 40), 40, 0, A.wtcr, 480, 32 * t, 32 * w, l16, q, acc);
  }
  epi_bias_store(acc, A.btcr, V, w, l16, q, false);
  __syncthreads();   // U,V visible to all

  // P3: T = tcr @ wv_p2t^T + bv_p2t
  zero_acc(acc);
#pragma unroll
  for (int kk = 0; kk < 4; ++kk)
    mfma_step<2>(V, 136, 32 * kk, A.wvp, 128, 32 * kk, 32 * w, l16, q, acc);
  epi_bias_store(acc, A.bvp, T, w, l16, q, false);

  // P4: H = pep @ wv_t2p^T + bv_t2p
  zero_acc(acc);
#pragma unroll
  for (int kk = 0; kk < 4; ++kk)
    mfma_step<2>(U, 136, 32 * kk, A.wvt, 128, 32 * kk, 32 * w, l16, q, acc);
  epi_bias_store(acc, A.bvt, H, w, l16, q, false);
  __syncthreads();   // T,H visible

  // P5: U = LN(pep + T @ wo_p2t^T + bo_p2t)  (pa0)
  zero_acc(acc);
#pragma unroll
  for (int kk = 0; kk < 4; ++kk)
    mfma_step<2>(T, 136, 32 * kk, A.wop, 128, 32 * kk, 32 * w, l16, q, acc);
  epi_res_ln(acc, A.bop, U, A.g1p, A.e1p, U, lnp, murs, w, l16, q, tid);

  // P6: V = LN(tcr + H @ wo_t2p^T + bo_t2p)  (ta0)
  zero_acc(acc);
#pragma unroll
  for (int kk = 0; kk < 4; ++kk)
    mfma_step<2>(H, 136, 32 * kk, A.wot, 128, 32 * kk, 32 * w, l16, q, acc);
  epi_res_ln(acc, A.bot, V, A.g1t, A.e1t, V, lnp, murs, w, l16, q, tid);

  // P7/P8: FFN blocks (internal barriers make U/V writes safe vs readers)
  ffn_block(A.w1p, A.w2p, A.b1p, A.b2p, A.g2p, A.e2p, U, H, lnp, murs, w, l16, q, tid);
  ffn_block(A.w1t, A.w2t, A.b1t, A.b2t, A.g2t, A.e2t, V, H, lnp, murs, w, l16, q, tid);
  __syncthreads();   // final U,V visible

  // P9: h1_pre = [pa|ta] @ w_h1^T + b_h1 ; BN1 partial stats ; store bf16
  zero_acc(acc);
#pragma unroll
  for (int s = 0; s < 8; ++s)
    mfma_step<2>((s < 4) ? U : V, 136, 32 * (s & 3), A.wh1, 256, 32 * s, 32 * w, l16, q, acc);
#pragma unroll
  for (int nt = 0; nt < 2; ++nt) {
    int col = 32 * w + 16 * nt + l16;
    float bb = A.bh1[col];
    float s = 0.f, sq = 0.f;
#pragma unroll
    for (int mt = 0; mt < 4; ++mt)
#pragma unroll
      for (int r = 0; r < 4; ++r) {
        float v = acc[mt][nt][r] + bb;
        s += v; sq += v * v;
        A.h1[(row0 + 16 * mt + 4 * q + r) * 128 + col] = f2b(v);
      }
    s += __shfl_xor(s, 16); sq += __shfl_xor(sq, 16);
    s += __shfl_xor(s, 32); sq += __shfl_xor(sq, 32);
    if (q == 0) {
      atomicAdd(&A.sum1[col], s);
      atomicAdd(&A.sq1[col], sq);
    }
  }
}

// ---------------------------------------------------------------------------
struct K2Args {
  const short* h1;
  const short* wh2;
  const float *bh2, *bn1g, *bn1b;
  const float *sum1, *sq1;
  float *sum2, *sq2;
  short* h2;
};

__global__ __launch_bounds__(256) void k2_main(K2Args A) {
  __shared__ __align__(16) short S2[64 * 136];
  __shared__ float s1[128], t1[128];
  const int tid = threadIdx.x;
  const int w = tid >> 6, lane = tid & 63, l16 = lane & 15, q = lane >> 4;
  const size_t row0 = (size_t)blockIdx.x * 64;

  if (tid < 128) {
    float su = A.sum1[tid], sq = A.sq1[tid];
    float mu = su * (1.0f / 65536.0f);
    float var = sq * (1.0f / 65536.0f) - mu * mu;
    float sc = A.bn1g[tid] * rsqrtf(var + 1e-5f);
    s1[tid] = sc;
    t1[tid] = A.bn1b[tid] - mu * sc;
  }
  __syncthreads();
  {
    int r = tid >> 2;
#pragma unroll
    for (int j = 0; j < 4; ++j) {
      int c = (tid & 3) * 32 + j * 8;
      s16x8 hv = *(const s16x8*)(A.h1 + (row0 + r) * 128 + c);
      s16x8 o;
#pragma unroll
      for (int i = 0; i < 8; ++i) {
        float f = b2f(hv[i]);
        f = gelu_f(f * s1[c + i] + t1[c + i]);
        o[i] = f2b(f);
      }
      *(s16x8*)(S2 + r * 136 + c) = o;
    }
  }
  __syncthreads();
  f32x4 acc[4][1];
  zero_acc(acc);
#pragma unroll
  for (int kk = 0; kk < 4; ++kk)
    mfma_step<1>(S2, 136, 32 * kk, A.wh2, 128, 32 * kk, 16 * w, l16, q, acc);
  int col = 16 * w + l16;
  float bb = A.bh2[col];
  float s = 0.f, sq = 0.f;
#pragma unroll
  for (int mt = 0; mt < 4; ++mt)
#pragma unroll
    for (int r = 0; r < 4; ++r) {
      float v = acc[mt][0][r] + bb;
      s += v; sq += v * v;
      A.h2[(row0 + 16 * mt + 4 * q + r) * 64 + col] = f2b(v);
    }
  s += __shfl_xor(s, 16); sq += __shfl_xor(sq, 16);
  s += __shfl_xor(s, 32); sq += __shfl_xor(sq, 32);
  if (q == 0) {
    atomicAdd(&A.sum2[col], s);
    atomicAdd(&A.sq2[col], sq);
  }
}

// ---------------------------------------------------------------------------
struct K3Args {
  const short* h2;
  const float *bn2g, *bn2b;
  const float *sum2, *sq2;
  const float *wout, *bout;
  float* out;
};

__global__ __launch_bounds__(256) void k3_main(K3Args A) {
  __shared__ float s2[64], t2[64], wo[64];
  const int tid = threadIdx.x;
  if (tid < 64) {
    float su = A.sum2[tid], sq = A.sq2[tid];
    float mu = su * (1.0f / 65536.0f);
    float var = sq * (1.0f / 65536.0f) - mu * mu;
    float sc = A.bn2g[tid] * rsqrtf(var + 1e-5f);
    s2[tid] = sc;
    t2[tid] = A.bn2b[tid] - mu * sc;
    wo[tid] = A.wout[tid];
  }
  __syncthreads();
  size_t row = (size_t)blockIdx.x * 32 + (tid >> 3);
  int c0 = (tid & 7) * 8;
  s16x8 hv = *(const s16x8*)(A.h2 + row * 64 + c0);
  float s = 0.f;
#pragma unroll
  for (int i = 0; i < 8; ++i) {
    float f = b2f(hv[i]);
    f = gelu_f(f * s2[c0 + i] + t2[c0 + i]);
    s += f * wo[c0 + i];
  }
  s += __shfl_xor(s, 1); s += __shfl_xor(s, 2); s += __shfl_xor(s, 4);
  if ((tid & 7) == 0) A.out[row] = s + A.bout[0];
}

// ---------------------------------------------------------------------------
struct CvtArgs {
  const float* src[12];
  short* dst;
  float* stats;
};

// Each block converts 1024 elements; all segment boundaries are multiples of
// 1024 so a block never straddles a segment. Block 0 also zeroes BN stats.
__global__ __launch_bounds__(256) void k0_setup(CvtArgs A) {
  const int cum[13] = {0, 49152, 110592, 126976, 143360, 159744, 176128,
                       241664, 307200, 372736, 438272, 471040, 479232};
  int b = blockIdx.x;
  if (b == 0) {
    A.stats[threadIdx.x] = 0.0f;
    if (threadIdx.x < 128) A.stats[256 + threadIdx.x] = 0.0f;
  }
  int base = b * 1024;
  int seg = 0;
#pragma unroll
  for (int t = 1; t < 12; ++t) seg += (base >= cum[t]) ? 1 : 0;
  const float* s = A.src[seg];
  int loc = base - cum[seg] + threadIdx.x * 4;
  float4 f = *(const float4*)(s + loc);
  int di = base + threadIdx.x * 4;
  A.dst[di + 0] = f2b(f.x);
  A.dst[di + 1] = f2b(f.y);
  A.dst[di + 2] = f2b(f.z);
  A.dst[di + 3] = f2b(f.w);
}

// ---------------------------------------------------------------------------
extern "C" void kernel_launch(void* const* d_in, const int* in_sizes, int n_in,
                              void* d_out, int out_size, void* d_ws, size_t ws_size,
                              hipStream_t stream) {
  (void)in_sizes; (void)n_in; (void)out_size; (void)ws_size;
  const float* x = (const float*)d_in[0];
  char* ws = (char*)d_ws;
  short* wb = (short*)ws;
  // bf16 weight segment offsets (elements)
  enum { O_PEP = 0, O_TCR = 49152, O_VP2T = 110592, O_OP2T = 126976,
         O_VT2P = 143360, O_OT2P = 159744, O_W1P = 176128, O_W2P = 241664,
         O_W1T = 307200, O_W2T = 372736, O_H1 = 438272, O_H2 = 471040 };
  float* stats = (float*)(ws + 958464);           // 384 floats
  short* h1_pre = (short*)(ws + 960000);          // 65536*128 bf16
  short* h2_pre = (short*)(ws + 17737216);        // 65536*64 bf16

  CvtArgs ca;
  ca.src[0]  = (const float*)d_in[1];   // w_pep
  ca.src[1]  = (const float*)d_in[3];   // w_tcr
  ca.src[2]  = (const float*)d_in[5];   // wv_p2t
  ca.src[3]  = (const float*)d_in[7];   // wo_p2t
  ca.src[4]  = (const float*)d_in[9];   // wv_t2p
  ca.src[5]  = (const float*)d_in[11];  // wo_t2p
  ca.src[6]  = (const float*)d_in[21];  // ffn_w1p
  ca.src[7]  = (const float*)d_in[23];  // ffn_w2p
  ca.src[8]  = (const float*)d_in[25];  // ffn_w1t
  ca.src[9]  = (const float*)d_in[27];  // ffn_w2t
  ca.src[10] = (const float*)d_in[29];  // w_h1
  ca.src[11] = (const float*)d_in[33];  // w_h2
  ca.dst = wb;
  ca.stats = stats;
  k0_setup<<<468, 256, 0, stream>>>(ca);

  K1Args a1;
  a1.x = x;
  a1.wpep = wb + O_PEP;  a1.wtcr = wb + O_TCR;
  a1.wvp = wb + O_VP2T;  a1.wop = wb + O_OP2T;
  a1.wvt = wb + O_VT2P;  a1.wot = wb + O_OT2P;
  a1.w1p = wb + O_W1P;   a1.w2p = wb + O_W2P;
  a1.w1t = wb + O_W1T;   a1.w2t = wb + O_W2T;
  a1.wh1 = wb + O_H1;
  a1.bpep = (const float*)d_in[2];
  a1.btcr = (const float*)d_in[4];
  a1.bvp = (const float*)d_in[6];
  a1.bop = (const float*)d_in[8];
  a1.bvt = (const float*)d_in[10];
  a1.bot = (const float*)d_in[12];
  a1.g1p = (const float*)d_in[13];  a1.e1p = (const float*)d_in[14];
  a1.g2p = (const float*)d_in[15];  a1.e2p = (const float*)d_in[16];
  a1.g1t = (const float*)d_in[17];  a1.e1t = (const float*)d_in[18];
  a1.g2t = (const float*)d_in[19];  a1.e2t = (const float*)d_in[20];
  a1.b1p = (const float*)d_in[22];
  a1.b2p = (const float*)d_in[24];
  a1.b1t = (const float*)d_in[26];
  a1.b2t = (const float*)d_in[28];
  a1.bh1 = (const float*)d_in[30];
  a1.sum1 = stats;
  a1.sq1 = stats + 128;
  a1.h1 = h1_pre;
  k1_main<<<1024, 256, 0, stream>>>(a1);

  K2Args a2;
  a2.h1 = h1_pre;
  a2.wh2 = wb + O_H2;
  a2.bh2 = (const float*)d_in[34];
  a2.bn1g = (const float*)d_in[31];
  a2.bn1b = (const float*)d_in[32];
  a2.sum1 = stats;
  a2.sq1 = stats + 128;
  a2.sum2 = stats + 256;
  a2.sq2 = stats + 320;
  a2.h2 = h2_pre;
  k2_main<<<1024, 256, 0, stream>>>(a2);

  K3Args a3;
  a3.h2 = h2_pre;
  a3.bn2g = (const float*)d_in[35];
  a3.bn2b = (const float*)d_in[36];
  a3.sum2 = stats + 256;
  a3.sq2 = stats + 320;
  a3.wout = (const float*)d_in[37];
  a3.bout = (const float*)d_in[38];
  a3.out = (float*)d_out;
  k3_main<<<2048, 256, 0, stream>>>(a3);
}